// Round 8
// baseline (1032.329 us; speedup 1.0000x reference)
//
#include <hip/hip_runtime.h>

#define N_NODES 100000
#define N_EDGES 300000
#define N_GRAPHS 2048
#define IN_DIM 38
#define HID 256
#define LAYERS 5
#define BN_EPS 1e-5f

#define SCAN_CHUNK 512
#define N_CHUNKS ((N_NODES + SCAN_CHUNK - 1) / SCAN_CHUNK)  // 196

// z-buffer (layer output) layout: INTERLEAVED u32 per channel:
//   word = hi_bf16 | (lo_bf16 << 16), row = 256 u32 = 1 KB.
// Two z-buffers ping-pong across layers.
#define ROW_PAD 128

typedef unsigned short u16;
typedef unsigned int u32;
typedef __attribute__((ext_vector_type(8))) short short8;       // 8 bf16 = 4 VGPR
typedef __attribute__((ext_vector_type(4))) unsigned short ushortx4;
typedef __attribute__((ext_vector_type(4))) unsigned int uintx4;
typedef __attribute__((ext_vector_type(4))) float floatx4;      // MFMA acc

__device__ __forceinline__ unsigned short bf16_rne(float f) {
    unsigned int u = __float_as_uint(f);
    unsigned int r = (u + 0x7fffu + ((u >> 16) & 1u)) >> 16;
    return (unsigned short)r;
}
__device__ __forceinline__ float uf(unsigned short b) {
    return __uint_as_float((unsigned int)b << 16);
}
__device__ __forceinline__ float unpack_pair(u32 w) {  // hi|lo<<16 -> value
    return uf((unsigned short)(w & 0xffffu)) + uf((unsigned short)(w >> 16));
}
__device__ __forceinline__ void split_bf16(float v, unsigned short& hi,
                                           unsigned short& lo) {
    hi = bf16_rne(v);
    float hf = __uint_as_float((unsigned int)hi << 16);
    lo = (unsigned short)(__float_as_uint(v - hf) >> 16);  // truncated residual
}
__device__ __forceinline__ u32 pack_pair(float v) {
    unsigned short hb, lb;
    split_bf16(v, hb, lb);
    return (u32)hb | ((u32)lb << 16);
}
// LDS byte-address swizzle applied on BOTH write (phase G) and read (P1).
// XORs high bits (8,9,12) into bank-slot bits (4,5,6); bijective within the
// 16KB plane; reads stay a 16B-slot permutation per 128B window.
__device__ __forceinline__ int swz(int b) {
    return b ^ (((b >> 8) & 3) << 4) ^ (((b >> 12) & 1) << 6);
}
// BN scale/shift for channel c from per-layer sums/sumsq
__device__ __forceinline__ void bn_params(const float* sums, const float* sumsq,
                                          const float* gammas,
                                          const float* betas, int c, float& sc,
                                          float& sh) {
    const float invN = 1.0f / (float)N_NODES;
    float mu = sums[c] * invN;
    float var = sumsq[c] * invN - mu * mu;
    float rs = rsqrtf(var + BN_EPS);
    float g = gammas[c];
    sc = rs * g;
    sh = betas[c] - mu * rs * g;
}

// ---------------- projection: h = x @ Wp + bp  ([N,38]@[38,256]) -------------
#define PROJ_CH 64
__global__ __launch_bounds__(256) void proj_kernel(
    const float* __restrict__ x, const float* __restrict__ Wp,
    const float* __restrict__ bp, u32* __restrict__ h) {
    __shared__ float xs[PROJ_CH * IN_DIM];
    int t = threadIdx.x;
    float w[IN_DIM];
#pragma unroll
    for (int k = 0; k < IN_DIM; k++) w[k] = Wp[k * HID + t];
    float b = bp[t];
    int n0 = blockIdx.x * PROJ_CH;
    int count = min(PROJ_CH, N_NODES - n0);
    int total = count * IN_DIM;
    const float* xbase = x + (size_t)n0 * IN_DIM;
    for (int i = t; i < total; i += 256) xs[i] = xbase[i];
    __syncthreads();
    for (int n = 0; n < count; n++) {
        float acc = b;
        const float* xr = &xs[n * IN_DIM];
#pragma unroll
        for (int k = 0; k < IN_DIM; k++) acc = fmaf(xr[k], w[k], acc);
        h[(size_t)(n0 + n) * 256 + t] = pack_pair(acc);
    }
}

// ---------------- CSR build --------------------------------------------------
__global__ __launch_bounds__(256) void hist_kernel(const int* __restrict__ ei,
                                                   int* __restrict__ deg) {
    int e = blockIdx.x * 256 + threadIdx.x;
    if (e < N_EDGES) atomicAdd(&deg[ei[N_EDGES + e]], 1);
}

__global__ __launch_bounds__(256) void scan1_kernel(const int* __restrict__ deg,
                                                    int* __restrict__ offs,
                                                    int* __restrict__ blocksums) {
    __shared__ int s[SCAN_CHUNK];
    int base = blockIdx.x * SCAN_CHUNK;
    int t = threadIdx.x;
    int i0 = t, i1 = t + 256;
    int g0 = base + i0, g1 = base + i1;
    int o0 = (g0 < N_NODES) ? deg[g0] : 0;
    int o1 = (g1 < N_NODES) ? deg[g1] : 0;
    s[i0] = o0;
    s[i1] = o1;
    __syncthreads();
    for (int off = 1; off < SCAN_CHUNK; off <<= 1) {
        int v0 = (i0 >= off) ? s[i0 - off] : 0;
        int v1 = (i1 >= off) ? s[i1 - off] : 0;
        __syncthreads();
        s[i0] += v0;
        s[i1] += v1;
        __syncthreads();
    }
    if (g0 < N_NODES) offs[g0] = s[i0] - o0;
    if (g1 < N_NODES) offs[g1] = s[i1] - o1;
    if (t == 0) blocksums[blockIdx.x] = s[SCAN_CHUNK - 1];
}

__global__ __launch_bounds__(256) void scan2_kernel(int* __restrict__ blocksums) {
    __shared__ int s[256];
    int t = threadIdx.x;
    int o = (t < N_CHUNKS) ? blocksums[t] : 0;
    s[t] = o;
    __syncthreads();
    for (int off = 1; off < 256; off <<= 1) {
        int v = (t >= off) ? s[t - off] : 0;
        __syncthreads();
        s[t] += v;
        __syncthreads();
    }
    if (t < N_CHUNKS) blocksums[t] = s[t] - o;
}

__global__ __launch_bounds__(256) void scan3_kernel(int* __restrict__ offs,
                                                    const int* __restrict__ blocksums,
                                                    int* __restrict__ cursor) {
    int g = blockIdx.x * 256 + threadIdx.x;
    if (g < N_NODES) {
        int v = offs[g] + blocksums[g / SCAN_CHUNK];
        offs[g] = v;
        cursor[g] = v;
    }
    if (g == 0) offs[N_NODES] = N_EDGES;
}

__global__ __launch_bounds__(256) void fill_kernel(const int* __restrict__ ei,
                                                   int* __restrict__ cursor,
                                                   int* __restrict__ csr_src) {
    int e = blockIdx.x * 256 + threadIdx.x;
    if (e < N_EDGES) {
        int src = ei[e];
        int dst = ei[N_EDGES + e];
        int pos = atomicAdd(&cursor[dst], 1);
        csr_src[pos] = src;
    }
}

// ---------------- weight packing: fragment-order bf16 hi/lo ------------------
__global__ __launch_bounds__(256) void packW_kernel(const float* __restrict__ W1s,
                                                    const float* __restrict__ W2s,
                                                    short8* __restrict__ Wpk8) {
    int id = blockIdx.x * 256 + threadIdx.x;  // < 81920
    int lane = id & 63;
    int fid = (id >> 6) & 127;
    int w = id >> 13;  // 0..9
    int kt = fid >> 4, nt = fid & 15;
    const float* Wsrc = (w < 5) ? W1s + (size_t)w * HID * HID
                                : W2s + (size_t)(w - 5) * HID * HID;
    int k0 = kt * 32 + ((lane >> 4) << 3);
    int n = nt * 16 + (lane & 15);
    short8 hi, lo;
#pragma unroll
    for (int e = 0; e < 8; e++) {
        float v = Wsrc[(size_t)(k0 + e) * HID + n];
        unsigned short hb, lb;
        split_bf16(v, hb, lb);
        hi[e] = (short)hb;
        lo[e] = (short)lb;
    }
    size_t base = (size_t)w * 16384;
    Wpk8[base + (size_t)((0 * 8 + kt) * 16 + nt) * 64 + lane] = hi;
    Wpk8[base + (size_t)((1 * 8 + kt) * 16 + nt) * 64 + lane] = lo;
}

// ------- fully fused layer: gather+BN+relu -> MLP -> stats -> z_l write ------
// Round 8: single change vs R7 — the z-output (C) stores are NON-TEMPORAL.
// Mechanism: zout (100 MB streaming) is not read until the NEXT dispatch, but
// cached write-allocate evicts zin from L3 mid-dispatch (FETCH 202 MB vs the
// 100 MB compulsory) and evicts W panels from the per-XCD L2. nt stores keep
// zin L3-resident for the gather's 4x row reuse and leave L2 to the W panels.
__global__ __launch_bounds__(256, 4) void fused_mlp_kernel(
    const u32* __restrict__ zin, const int* __restrict__ offs,
    const int* __restrict__ csr_src, const float* __restrict__ eps, int layer,
    const float* __restrict__ psums, const float* __restrict__ psumsq,
    const float* __restrict__ pgam, const float* __restrict__ pbet, int useBN,
    const short8* __restrict__ W1m, const float* __restrict__ b1,
    const short8* __restrict__ W2m, const float* __restrict__ b2,
    u32* __restrict__ C, int M, float* __restrict__ sums,
    float* __restrict__ sumsq) {
    __shared__ char lds[32768];
    u16* Hf = (u16*)lds;      // P2/P3 overlay
    float* cf = (float*)lds;  // P4 overlay
    int t = threadIdx.x;
    int lane = t & 63;
    int w = t >> 6;
    int m0 = blockIdx.x * 32;
    int col15 = lane & 15;
    int rgrp = lane >> 4;

    // ---------------- Phase G: dual-node interleaved gather ----------------
    {
        float gs = 1.0f + eps[layer];
        int c0 = lane * 4;
        float4 sc = make_float4(1.f, 1.f, 1.f, 1.f);
        float4 sh = make_float4(0.f, 0.f, 0.f, 0.f);
        if (useBN) {
            bn_params(psums, psumsq, pgam, pbet, c0 + 0, sc.x, sh.x);
            bn_params(psums, psumsq, pgam, pbet, c0 + 1, sc.y, sh.y);
            bn_params(psums, psumsq, pgam, pbet, c0 + 2, sc.z, sh.z);
            bn_params(psums, psumsq, pgam, pbet, c0 + 3, sc.w, sh.w);
        }
        // wave w handles nodes m0 + w*8 + g (g<8): mt = w>>1, row = (w&1)*8+g
        int fb0 = ((lane >> 3) * 2 + (w >> 1)) * 1024 + ((lane >> 1) & 3) * 256 +
                  (lane & 1) * 8 + (w & 1) * 128;
        int nb = m0 + w * 8;

#define BNREL(vv)                                                     \
        if (useBN) {                                                  \
            vv[0] = fmaxf(vv[0] * sc.x + sh.x, 0.f);                  \
            vv[1] = fmaxf(vv[1] * sc.y + sh.y, 0.f);                  \
            vv[2] = fmaxf(vv[2] * sc.z + sh.z, 0.f);                  \
            vv[3] = fmaxf(vv[3] * sc.w + sh.w, 0.f);                  \
        }
#define PROCR(rv, av)                                                 \
        {                                                             \
            float v0 = unpack_pair(rv[0]);                            \
            float v1 = unpack_pair(rv[1]);                            \
            float v2 = unpack_pair(rv[2]);                            \
            float v3 = unpack_pair(rv[3]);                            \
            if (useBN) {                                              \
                v0 = fmaxf(v0 * sc.x + sh.x, 0.f);                    \
                v1 = fmaxf(v1 * sc.y + sh.y, 0.f);                    \
                v2 = fmaxf(v2 * sc.z + sh.z, 0.f);                    \
                v3 = fmaxf(v3 * sc.w + sh.w, 0.f);                    \
            }                                                         \
            av[0] += v0; av[1] += v1; av[2] += v2; av[3] += v3;       \
        }

        for (int p = 0; p < 4; p++) {
            int nA = nb + 2 * p;
            int nB = nA + 1;
            // issue both self rows + both offset pairs up front
            int begA = offs[nA], endA = offs[nA + 1];
            int begB = offs[nB], endB = offs[nB + 1];
            uintx4 vsA = *(const uintx4*)&zin[(size_t)nA * 256 + c0];
            uintx4 vsB = *(const uintx4*)&zin[(size_t)nB * 256 + c0];
            float aA[4], aB[4];
            aA[0] = unpack_pair(vsA[0]);
            aA[1] = unpack_pair(vsA[1]);
            aA[2] = unpack_pair(vsA[2]);
            aA[3] = unpack_pair(vsA[3]);
            BNREL(aA);
            aA[0] *= gs; aA[1] *= gs; aA[2] *= gs; aA[3] *= gs;
            aB[0] = unpack_pair(vsB[0]);
            aB[1] = unpack_pair(vsB[1]);
            aB[2] = unpack_pair(vsB[2]);
            aB[3] = unpack_pair(vsB[3]);
            BNREL(aB);
            aB[0] *= gs; aB[1] *= gs; aB[2] *= gs; aB[3] *= gs;

            int baseA = begA, baseB = begB;
            while (baseA < endA || baseB < endB) {
                bool actA = baseA < endA, actB = baseB < endB;
                int iA0 = 0, iA1 = 0, iA2 = 0, iA3 = 0;
                int iB0 = 0, iB1 = 0, iB2 = 0, iB3 = 0;
                // index round: issue A's and B's csr loads back-to-back
                if (actA) {
                    iA0 = csr_src[baseA];
                    iA1 = (baseA + 1 < endA) ? csr_src[baseA + 1] : iA0;
                    iA2 = (baseA + 2 < endA) ? csr_src[baseA + 2] : iA0;
                    iA3 = (baseA + 3 < endA) ? csr_src[baseA + 3] : iA0;
                }
                if (actB) {
                    iB0 = csr_src[baseB];
                    iB1 = (baseB + 1 < endB) ? csr_src[baseB + 1] : iB0;
                    iB2 = (baseB + 2 < endB) ? csr_src[baseB + 2] : iB0;
                    iB3 = (baseB + 3 < endB) ? csr_src[baseB + 3] : iB0;
                }
                // row round: issue all 8 row loads before any processing
                uintx4 rA0, rA1, rA2, rA3, rB0, rB1, rB2, rB3;
                if (actA) {
                    rA0 = *(const uintx4*)&zin[(size_t)iA0 * 256 + c0];
                    rA1 = *(const uintx4*)&zin[(size_t)iA1 * 256 + c0];
                    rA2 = *(const uintx4*)&zin[(size_t)iA2 * 256 + c0];
                    rA3 = *(const uintx4*)&zin[(size_t)iA3 * 256 + c0];
                }
                if (actB) {
                    rB0 = *(const uintx4*)&zin[(size_t)iB0 * 256 + c0];
                    rB1 = *(const uintx4*)&zin[(size_t)iB1 * 256 + c0];
                    rB2 = *(const uintx4*)&zin[(size_t)iB2 * 256 + c0];
                    rB3 = *(const uintx4*)&zin[(size_t)iB3 * 256 + c0];
                }
                if (actA) {
                    PROCR(rA0, aA);
                    if (baseA + 1 < endA) PROCR(rA1, aA);
                    if (baseA + 2 < endA) PROCR(rA2, aA);
                    if (baseA + 3 < endA) PROCR(rA3, aA);
                    baseA += 4;
                }
                if (actB) {
                    PROCR(rB0, aB);
                    if (baseB + 1 < endB) PROCR(rB1, aB);
                    if (baseB + 2 < endB) PROCR(rB2, aB);
                    if (baseB + 3 < endB) PROCR(rB3, aB);
                    baseB += 4;
                }
            }
            // split + swizzled fragment writes (slots 2p and 2p+1)
            ushortx4 hoA, loA, hoB, loB;
#pragma unroll
            for (int q = 0; q < 4; q++) {
                unsigned short hb, lb;
                split_bf16(aA[q], hb, lb);
                hoA[q] = hb;
                loA[q] = lb;
                split_bf16(aB[q], hb, lb);
                hoB[q] = hb;
                loB[q] = lb;
            }
            int sbA = swz(fb0 + (2 * p) * 16);
            int sbB = swz(fb0 + (2 * p + 1) * 16);
            *(ushortx4*)(lds + sbA) = hoA;
            *(ushortx4*)(lds + sbA + 16384) = loA;
            *(ushortx4*)(lds + sbB) = hoB;
            *(ushortx4*)(lds + sbB + 16384) = loB;
        }
#undef BNREL
#undef PROCR
    }
    __syncthreads();

    // ---------------- P1: acc = Z @ W1 (barrier-free) ----------------------
    floatx4 acc[2][4];
#pragma unroll
    for (int i = 0; i < 2; i++)
#pragma unroll
        for (int j = 0; j < 4; j++) acc[i][j] = (floatx4)0.0f;

#pragma unroll
    for (int kk = 0; kk < 8; kk++) {
        short8 bb0[4], bb1[4];
#pragma unroll
        for (int j = 0; j < 4; j++) {
            bb0[j] = W1m[((size_t)(0 * 8 + kk) * 16 + (w * 4 + j)) * 64 + lane];
            bb1[j] = W1m[((size_t)(1 * 8 + kk) * 16 + (w * 4 + j)) * 64 + lane];
        }
        short8 ah[2], al[2];
#pragma unroll
        for (int mt = 0; mt < 2; mt++) {
            int ib = swz(((kk * 2 + mt) * 64 + lane) * 16);
            ah[mt] = *(short8*)(lds + ib);
            al[mt] = *(short8*)(lds + ib + 16384);
        }
        __builtin_amdgcn_s_setprio(1);
#pragma unroll
        for (int i = 0; i < 2; i++)
#pragma unroll
            for (int j = 0; j < 4; j++) {
                acc[i][j] = __builtin_amdgcn_mfma_f32_16x16x32_bf16(
                    ah[i], bb0[j], acc[i][j], 0, 0, 0);
                acc[i][j] = __builtin_amdgcn_mfma_f32_16x16x32_bf16(
                    ah[i], bb1[j], acc[i][j], 0, 0, 0);
                acc[i][j] = __builtin_amdgcn_mfma_f32_16x16x32_bf16(
                    al[i], bb0[j], acc[i][j], 0, 0, 0);
            }
        __builtin_amdgcn_s_setprio(0);
    }
    __syncthreads();  // Zf dead; Hf takes over

    // ---------------- P2: H = relu(acc + b1) -> A-frag split LDS -----------
#pragma unroll
    for (int j = 0; j < 4; j++) {
        int col = w * 64 + j * 16 + col15;
        float bv = b1[col];
        int kt2 = col >> 5;
        int colg = (col & 31) >> 3;
        int e = col & 7;
#pragma unroll
        for (int i = 0; i < 2; i++) {
            int lane_a = rgrp * 4 + colg * 16;
#pragma unroll
            for (int r = 0; r < 4; r++) {
                float v = fmaxf(acc[i][j][r] + bv, 0.0f);
                unsigned short hb, lb;
                split_bf16(v, hb, lb);
                Hf[(((0 * 8 + kt2) * 2 + i) * 64 + lane_a + r) * 8 + e] = hb;
                Hf[(((1 * 8 + kt2) * 2 + i) * 64 + lane_a + r) * 8 + e] = lb;
            }
        }
    }
    __syncthreads();

    // ---------------- P3: acc2 = H @ W2 (barrier-free) ---------------------
    floatx4 acc2[2][4];
#pragma unroll
    for (int i = 0; i < 2; i++)
#pragma unroll
        for (int j = 0; j < 4; j++) acc2[i][j] = (floatx4)0.0f;

#pragma unroll
    for (int kj = 0; kj < 8; kj++) {
        short8 bb2[2][4];
#pragma unroll
        for (int p = 0; p < 2; p++)
#pragma unroll
            for (int j = 0; j < 4; j++)
                bb2[p][j] =
                    W2m[((size_t)(p * 8 + kj) * 16 + (w * 4 + j)) * 64 + lane];
        short8 ah2[2], al2[2];
#pragma unroll
        for (int mt = 0; mt < 2; mt++) {
            ah2[mt] = *(short8*)&Hf[(((0 * 8 + kj) * 2 + mt) * 64 + lane) * 8];
            al2[mt] = *(short8*)&Hf[(((1 * 8 + kj) * 2 + mt) * 64 + lane) * 8];
        }
        __builtin_amdgcn_s_setprio(1);
#pragma unroll
        for (int i = 0; i < 2; i++)
#pragma unroll
            for (int j = 0; j < 4; j++) {
                acc2[i][j] = __builtin_amdgcn_mfma_f32_16x16x32_bf16(
                    ah2[i], bb2[0][j], acc2[i][j], 0, 0, 0);
                acc2[i][j] = __builtin_amdgcn_mfma_f32_16x16x32_bf16(
                    ah2[i], bb2[1][j], acc2[i][j], 0, 0, 0);
                acc2[i][j] = __builtin_amdgcn_mfma_f32_16x16x32_bf16(
                    al2[i], bb2[0][j], acc2[i][j], 0, 0, 0);
            }
        __builtin_amdgcn_s_setprio(0);
    }
    __syncthreads();  // Hf dead; cf takes over

    // ---------------- P4: stats + LDS transpose + NT interleaved write -----
#pragma unroll
    for (int j = 0; j < 4; j++) {
        int col = w * 64 + j * 16 + col15;
        float bv = b2[col];
        float csum = 0.f, csq = 0.f;
#pragma unroll
        for (int i = 0; i < 2; i++) {
            int rowb = i * 16 + rgrp * 4;
#pragma unroll
            for (int r = 0; r < 4; r++) {
                float v = acc2[i][j][r] + bv;
                cf[(rowb + r) * 256 + col] = v;
                if (m0 + rowb + r < M) {
                    csum += v;
                    csq += v * v;
                }
            }
        }
        csum += __shfl_xor(csum, 16);
        csum += __shfl_xor(csum, 32);
        csq += __shfl_xor(csq, 16);
        csq += __shfl_xor(csq, 32);
        if (rgrp == 0) {
            atomicAdd(&sums[col], csum);
            atomicAdd(&sumsq[col], csq);
        }
    }
    __syncthreads();
#pragma unroll
    for (int k = 0; k < 8; k++) {
        int fi = (k * 256 + t) * 4;  // flat float idx in 32x256 tile
        int row = fi >> 8, colc = fi & 255;
        int m = m0 + row;
        if (m >= M) continue;
        float4 v4 = *(float4*)&cf[fi];
        uintx4 o;
        o[0] = pack_pair(v4.x);
        o[1] = pack_pair(v4.y);
        o[2] = pack_pair(v4.z);
        o[3] = pack_pair(v4.w);
        // NT store: zout isn't read until the next dispatch; don't let its
        // write-allocate evict zin (L3) or the W panels (L2).
        __builtin_nontemporal_store(o, (uintx4*)&C[(size_t)m * 256 + colc]);
    }
}

// ---------------- pooling (batch sorted), fused final BN+relu ----------------
__global__ __launch_bounds__(256) void bounds_kernel(const int* __restrict__ batch,
                                                     int* __restrict__ start) {
    int g = blockIdx.x * 256 + threadIdx.x;
    if (g > N_GRAPHS) return;
    int lo = 0, hi = N_NODES;
    while (lo < hi) {
        int mid = (lo + hi) >> 1;
        if (batch[mid] < g) lo = mid + 1;
        else hi = mid;
    }
    start[g] = lo;
}

__global__ __launch_bounds__(256) void segpool_kernel(
    const u32* __restrict__ z, const int* __restrict__ start,
    const float* __restrict__ sums, const float* __restrict__ sumsq,
    const float* __restrict__ gammas, const float* __restrict__ betas,
    float* __restrict__ pooled) {
    int g = blockIdx.x;
    int c = threadIdx.x;
    float sc, sh;
    bn_params(sums, sumsq, gammas, betas, c, sc, sh);
    int beg = start[g], end = start[g + 1];
    float s = 0.f;
    for (int n = beg; n < end; n++) {
        float v = unpack_pair(z[(size_t)n * 256 + c]);
        s += fmaxf(v * sc + sh, 0.f);
    }
    float inv = 1.0f / fmaxf((float)(end - beg), 1.0f);
    pooled[(size_t)g * HID + c] = s * inv;
}

// ---------------- readout: 8 graphs per block (Wr1 read 256x fewer times) ----
#define RGK 8
__global__ __launch_bounds__(256) void readout_kernel(
    const float* __restrict__ pooled, const float* __restrict__ Wr1,
    const float* __restrict__ br1, const float* __restrict__ Wr2,
    const float* __restrict__ br2, float* __restrict__ out) {
    __shared__ float p[RGK][HID];
    __shared__ float red[RGK][4];
    int g0 = blockIdx.x * RGK;
    int t = threadIdx.x;
#pragma unroll
    for (int q = 0; q < RGK; q++) p[q][t] = pooled[(size_t)(g0 + q) * HID + t];
    __syncthreads();
    int c = t;
    float acc[RGK];
#pragma unroll
    for (int q = 0; q < RGK; q++) acc[q] = br1[c];
    for (int k = 0; k < HID; k++) {
        float wv = Wr1[k * HID + c];
#pragma unroll
        for (int q = 0; q < RGK; q++) acc[q] = fmaf(p[q][k], wv, acc[q]);
    }
    float w2 = Wr2[c];
#pragma unroll
    for (int q = 0; q < RGK; q++) {
        float v = fmaxf(acc[q], 0.f) * w2;
#pragma unroll
        for (int off = 32; off > 0; off >>= 1) v += __shfl_down(v, off, 64);
        if ((c & 63) == 0) red[q][c >> 6] = v;
    }
    __syncthreads();
    if (t < RGK)
        out[g0 + t] = red[t][0] + red[t][1] + red[t][2] + red[t][3] + br2[0];
}

extern "C" void kernel_launch(void* const* d_in, const int* in_sizes, int n_in,
                              void* d_out, int out_size, void* d_ws, size_t ws_size,
                              hipStream_t stream) {
    const float* x      = (const float*)d_in[0];
    const int*   ei     = (const int*)d_in[1];
    const int*   batch  = (const int*)d_in[2];
    const float* Wp     = (const float*)d_in[3];
    const float* bp     = (const float*)d_in[4];
    const float* eps    = (const float*)d_in[5];
    const float* W1s    = (const float*)d_in[6];
    const float* b1s    = (const float*)d_in[7];
    const float* W2s    = (const float*)d_in[8];
    const float* b2s    = (const float*)d_in[9];
    const float* gammas = (const float*)d_in[10];
    const float* betas  = (const float*)d_in[11];
    const float* Wr1    = (const float*)d_in[12];
    const float* br1    = (const float*)d_in[13];
    const float* Wr2    = (const float*)d_in[14];
    const float* br2    = (const float*)d_in[15];
    float* out = (float*)d_out;

    const size_t ROWS = (size_t)N_NODES + ROW_PAD;
    u32* bufA     = (u32*)d_ws;                    // z ping buffer, interleaved
    u32* bufC     = bufA + ROWS * 256;             // z pong buffer, interleaved
    short8* Wpk8  = (short8*)(bufC + ROWS * 256);  // 10*16384 short8 = 2.62 MB
    float* sums   = (float*)(Wpk8 + 10 * 16384);   // LAYERS*512 (sum|sumsq)
    float* pooled = sums + LAYERS * 512;
    int* start     = (int*)(pooled + (size_t)N_GRAPHS * HID);  // N_GRAPHS+1
    int* deg       = start + N_GRAPHS + 1;
    int* offs      = deg + N_NODES;        // N_NODES+1
    int* cursor    = offs + N_NODES + 1;
    int* csr_src   = cursor + N_NODES;
    int* blocksums = csr_src + N_EDGES;    // N_CHUNKS

    // ---- CSR build + weight packing + zeroing (once per launch) ----
    hipMemsetAsync(deg, 0, N_NODES * sizeof(int), stream);
    hipMemsetAsync(sums, 0, LAYERS * 512 * sizeof(float), stream);
    hist_kernel<<<(N_EDGES + 255) / 256, 256, 0, stream>>>(ei, deg);
    scan1_kernel<<<N_CHUNKS, 256, 0, stream>>>(deg, offs, blocksums);
    scan2_kernel<<<1, 256, 0, stream>>>(blocksums);
    scan3_kernel<<<(N_NODES + 255) / 256, 256, 0, stream>>>(offs, blocksums,
                                                            cursor);
    fill_kernel<<<(N_EDGES + 255) / 256, 256, 0, stream>>>(ei, cursor, csr_src);
    packW_kernel<<<320, 256, 0, stream>>>(W1s, W2s, Wpk8);
    bounds_kernel<<<(N_GRAPHS + 1 + 255) / 256, 256, 0, stream>>>(batch, start);

    // h0 = x @ Wp + bp  -> bufA (interleaved)
    proj_kernel<<<(N_NODES + PROJ_CH - 1) / PROJ_CH, 256, 0, stream>>>(x, Wp, bp,
                                                                       bufA);

    const int MLP_BLOCKS = (N_NODES + 31) / 32;  // 3125, exact (no tail)
    u32* zin = bufA;
    u32* zout = bufC;
    for (int l = 0; l < LAYERS; l++) {
        float* lsums = sums + l * 512;
        float* lsumsq = lsums + 256;
        const float* psums = sums + (l - 1) * 512;  // valid only for l>0
        fused_mlp_kernel<<<MLP_BLOCKS, 256, 0, stream>>>(
            zin, offs, csr_src, eps, l,
            l > 0 ? psums : sums, l > 0 ? psums + 256 : sums,
            gammas + (l > 0 ? (l - 1) : 0) * HID,
            betas + (l > 0 ? (l - 1) : 0) * HID, l > 0 ? 1 : 0,
            Wpk8 + (size_t)l * 16384, b1s + l * HID,
            Wpk8 + (size_t)(5 + l) * 16384, b2s + l * HID, zout, N_NODES,
            lsums, lsumsq);
        u32* tmp = zin; zin = zout; zout = tmp;
    }
    // after 5 swaps, zin holds the final layer output

    segpool_kernel<<<N_GRAPHS, 256, 0, stream>>>(
        zin, start, sums + 4 * 512, sums + 4 * 512 + 256, gammas + 4 * HID,
        betas + 4 * HID, pooled);
    readout_kernel<<<N_GRAPHS / RGK, 256, 0, stream>>>(pooled, Wr1, br1, Wr2, br2,
                                                       out);
}

// Round 9
// 1005.684 us; speedup vs baseline: 1.0265x; 1.0265x over previous
//
#include <hip/hip_runtime.h>

#define N_NODES 100000
#define N_EDGES 300000
#define N_GRAPHS 2048
#define IN_DIM 38
#define HID 256
#define LAYERS 5
#define BN_EPS 1e-5f

#define SCAN_CHUNK 512
#define N_CHUNKS ((N_NODES + SCAN_CHUNK - 1) / SCAN_CHUNK)  // 196

// z-buffer (layer output) layout: INTERLEAVED u32 per channel:
//   word = hi_bf16 | (lo_bf16 << 16), row = 256 u32 = 1 KB.
// Two z-buffers ping-pong across layers.
#define ROW_PAD 128

typedef unsigned short u16;
typedef unsigned int u32;
typedef __attribute__((ext_vector_type(8))) short short8;       // 8 bf16 = 4 VGPR
typedef __attribute__((ext_vector_type(4))) unsigned short ushortx4;
typedef __attribute__((ext_vector_type(4))) unsigned int uintx4;
typedef __attribute__((ext_vector_type(4))) float floatx4;      // MFMA acc

__device__ __forceinline__ unsigned short bf16_rne(float f) {
    unsigned int u = __float_as_uint(f);
    unsigned int r = (u + 0x7fffu + ((u >> 16) & 1u)) >> 16;
    return (unsigned short)r;
}
__device__ __forceinline__ float uf(unsigned short b) {
    return __uint_as_float((unsigned int)b << 16);
}
__device__ __forceinline__ float unpack_pair(u32 w) {  // hi|lo<<16 -> value
    return uf((unsigned short)(w & 0xffffu)) + uf((unsigned short)(w >> 16));
}
__device__ __forceinline__ void split_bf16(float v, unsigned short& hi,
                                           unsigned short& lo) {
    hi = bf16_rne(v);
    float hf = __uint_as_float((unsigned int)hi << 16);
    lo = (unsigned short)(__float_as_uint(v - hf) >> 16);  // truncated residual
}
__device__ __forceinline__ u32 pack_pair(float v) {
    unsigned short hb, lb;
    split_bf16(v, hb, lb);
    return (u32)hb | ((u32)lb << 16);
}
// LDS byte-address swizzle applied on BOTH write (phase G) and read (P1).
// XORs high bits (8,9,12) into bank-slot bits (4,5,6); bijective within the
// 16KB plane; reads stay a 16B-slot permutation per 128B window.
__device__ __forceinline__ int swz(int b) {
    return b ^ (((b >> 8) & 3) << 4) ^ (((b >> 12) & 1) << 6);
}
// BN scale/shift for channel c from per-layer sums/sumsq
__device__ __forceinline__ void bn_params(const float* sums, const float* sumsq,
                                          const float* gammas,
                                          const float* betas, int c, float& sc,
                                          float& sh) {
    const float invN = 1.0f / (float)N_NODES;
    float mu = sums[c] * invN;
    float var = sumsq[c] * invN - mu * mu;
    float rs = rsqrtf(var + BN_EPS);
    float g = gammas[c];
    sc = rs * g;
    sh = betas[c] - mu * rs * g;
}

// ---------------- projection: h = x @ Wp + bp  ([N,38]@[38,256]) -------------
#define PROJ_CH 64
__global__ __launch_bounds__(256) void proj_kernel(
    const float* __restrict__ x, const float* __restrict__ Wp,
    const float* __restrict__ bp, u32* __restrict__ h) {
    __shared__ float xs[PROJ_CH * IN_DIM];
    int t = threadIdx.x;
    float w[IN_DIM];
#pragma unroll
    for (int k = 0; k < IN_DIM; k++) w[k] = Wp[k * HID + t];
    float b = bp[t];
    int n0 = blockIdx.x * PROJ_CH;
    int count = min(PROJ_CH, N_NODES - n0);
    int total = count * IN_DIM;
    const float* xbase = x + (size_t)n0 * IN_DIM;
    for (int i = t; i < total; i += 256) xs[i] = xbase[i];
    __syncthreads();
    for (int n = 0; n < count; n++) {
        float acc = b;
        const float* xr = &xs[n * IN_DIM];
#pragma unroll
        for (int k = 0; k < IN_DIM; k++) acc = fmaf(xr[k], w[k], acc);
        h[(size_t)(n0 + n) * 256 + t] = pack_pair(acc);
    }
}

// ---------------- CSR build --------------------------------------------------
__global__ __launch_bounds__(256) void hist_kernel(const int* __restrict__ ei,
                                                   int* __restrict__ deg) {
    int e = blockIdx.x * 256 + threadIdx.x;
    if (e < N_EDGES) atomicAdd(&deg[ei[N_EDGES + e]], 1);
}

__global__ __launch_bounds__(256) void scan1_kernel(const int* __restrict__ deg,
                                                    int* __restrict__ offs,
                                                    int* __restrict__ blocksums) {
    __shared__ int s[SCAN_CHUNK];
    int base = blockIdx.x * SCAN_CHUNK;
    int t = threadIdx.x;
    int i0 = t, i1 = t + 256;
    int g0 = base + i0, g1 = base + i1;
    int o0 = (g0 < N_NODES) ? deg[g0] : 0;
    int o1 = (g1 < N_NODES) ? deg[g1] : 0;
    s[i0] = o0;
    s[i1] = o1;
    __syncthreads();
    for (int off = 1; off < SCAN_CHUNK; off <<= 1) {
        int v0 = (i0 >= off) ? s[i0 - off] : 0;
        int v1 = (i1 >= off) ? s[i1 - off] : 0;
        __syncthreads();
        s[i0] += v0;
        s[i1] += v1;
        __syncthreads();
    }
    if (g0 < N_NODES) offs[g0] = s[i0] - o0;
    if (g1 < N_NODES) offs[g1] = s[i1] - o1;
    if (t == 0) blocksums[blockIdx.x] = s[SCAN_CHUNK - 1];
}

__global__ __launch_bounds__(256) void scan2_kernel(int* __restrict__ blocksums) {
    __shared__ int s[256];
    int t = threadIdx.x;
    int o = (t < N_CHUNKS) ? blocksums[t] : 0;
    s[t] = o;
    __syncthreads();
    for (int off = 1; off < 256; off <<= 1) {
        int v = (t >= off) ? s[t - off] : 0;
        __syncthreads();
        s[t] += v;
        __syncthreads();
    }
    if (t < N_CHUNKS) blocksums[t] = s[t] - o;
}

__global__ __launch_bounds__(256) void scan3_kernel(int* __restrict__ offs,
                                                    const int* __restrict__ blocksums,
                                                    int* __restrict__ cursor) {
    int g = blockIdx.x * 256 + threadIdx.x;
    if (g < N_NODES) {
        int v = offs[g] + blocksums[g / SCAN_CHUNK];
        offs[g] = v;
        cursor[g] = v;
    }
    if (g == 0) offs[N_NODES] = N_EDGES;
}

__global__ __launch_bounds__(256) void fill_kernel(const int* __restrict__ ei,
                                                   int* __restrict__ cursor,
                                                   int* __restrict__ csr_src) {
    int e = blockIdx.x * 256 + threadIdx.x;
    if (e < N_EDGES) {
        int src = ei[e];
        int dst = ei[N_EDGES + e];
        int pos = atomicAdd(&cursor[dst], 1);
        csr_src[pos] = src;
    }
}

// ---------------- weight packing: fragment-order bf16 hi/lo ------------------
__global__ __launch_bounds__(256) void packW_kernel(const float* __restrict__ W1s,
                                                    const float* __restrict__ W2s,
                                                    short8* __restrict__ Wpk8) {
    int id = blockIdx.x * 256 + threadIdx.x;  // < 81920
    int lane = id & 63;
    int fid = (id >> 6) & 127;
    int w = id >> 13;  // 0..9
    int kt = fid >> 4, nt = fid & 15;
    const float* Wsrc = (w < 5) ? W1s + (size_t)w * HID * HID
                                : W2s + (size_t)(w - 5) * HID * HID;
    int k0 = kt * 32 + ((lane >> 4) << 3);
    int n = nt * 16 + (lane & 15);
    short8 hi, lo;
#pragma unroll
    for (int e = 0; e < 8; e++) {
        float v = Wsrc[(size_t)(k0 + e) * HID + n];
        unsigned short hb, lb;
        split_bf16(v, hb, lb);
        hi[e] = (short)hb;
        lo[e] = (short)lb;
    }
    size_t base = (size_t)w * 16384;
    Wpk8[base + (size_t)((0 * 8 + kt) * 16 + nt) * 64 + lane] = hi;
    Wpk8[base + (size_t)((1 * 8 + kt) * 16 + nt) * 64 + lane] = lo;
}

// ------- fully fused layer: gather+BN+relu -> MLP -> stats -> z_l write ------
// Round 9: revert to R7 exactly (best measured config, 1015 us): 32-row tile,
// 4 blocks/CU, dual-node interleaved gather, plain cached stores (R8's nt
// store was null on FETCH and dur). Structure notes: G-phase z-row service is
// a measured invariant ~5.3 TB/s across all structures tried; MFMA busy time
// is at its 38 us/layer analytic floor; overlap attempts (registers / phases)
// exhausted -> this is the practical plateau of the structure.
__global__ __launch_bounds__(256, 4) void fused_mlp_kernel(
    const u32* __restrict__ zin, const int* __restrict__ offs,
    const int* __restrict__ csr_src, const float* __restrict__ eps, int layer,
    const float* __restrict__ psums, const float* __restrict__ psumsq,
    const float* __restrict__ pgam, const float* __restrict__ pbet, int useBN,
    const short8* __restrict__ W1m, const float* __restrict__ b1,
    const short8* __restrict__ W2m, const float* __restrict__ b2,
    u32* __restrict__ C, int M, float* __restrict__ sums,
    float* __restrict__ sumsq) {
    __shared__ char lds[32768];
    u16* Hf = (u16*)lds;      // P2/P3 overlay
    float* cf = (float*)lds;  // P4 overlay
    int t = threadIdx.x;
    int lane = t & 63;
    int w = t >> 6;
    int m0 = blockIdx.x * 32;
    int col15 = lane & 15;
    int rgrp = lane >> 4;

    // ---------------- Phase G: dual-node interleaved gather ----------------
    {
        float gs = 1.0f + eps[layer];
        int c0 = lane * 4;
        float4 sc = make_float4(1.f, 1.f, 1.f, 1.f);
        float4 sh = make_float4(0.f, 0.f, 0.f, 0.f);
        if (useBN) {
            bn_params(psums, psumsq, pgam, pbet, c0 + 0, sc.x, sh.x);
            bn_params(psums, psumsq, pgam, pbet, c0 + 1, sc.y, sh.y);
            bn_params(psums, psumsq, pgam, pbet, c0 + 2, sc.z, sh.z);
            bn_params(psums, psumsq, pgam, pbet, c0 + 3, sc.w, sh.w);
        }
        // wave w handles nodes m0 + w*8 + g (g<8): mt = w>>1, row = (w&1)*8+g
        int fb0 = ((lane >> 3) * 2 + (w >> 1)) * 1024 + ((lane >> 1) & 3) * 256 +
                  (lane & 1) * 8 + (w & 1) * 128;
        int nb = m0 + w * 8;

#define BNREL(vv)                                                     \
        if (useBN) {                                                  \
            vv[0] = fmaxf(vv[0] * sc.x + sh.x, 0.f);                  \
            vv[1] = fmaxf(vv[1] * sc.y + sh.y, 0.f);                  \
            vv[2] = fmaxf(vv[2] * sc.z + sh.z, 0.f);                  \
            vv[3] = fmaxf(vv[3] * sc.w + sh.w, 0.f);                  \
        }
#define PROCR(rv, av)                                                 \
        {                                                             \
            float v0 = unpack_pair(rv[0]);                            \
            float v1 = unpack_pair(rv[1]);                            \
            float v2 = unpack_pair(rv[2]);                            \
            float v3 = unpack_pair(rv[3]);                            \
            if (useBN) {                                              \
                v0 = fmaxf(v0 * sc.x + sh.x, 0.f);                    \
                v1 = fmaxf(v1 * sc.y + sh.y, 0.f);                    \
                v2 = fmaxf(v2 * sc.z + sh.z, 0.f);                    \
                v3 = fmaxf(v3 * sc.w + sh.w, 0.f);                    \
            }                                                         \
            av[0] += v0; av[1] += v1; av[2] += v2; av[3] += v3;       \
        }

        for (int p = 0; p < 4; p++) {
            int nA = nb + 2 * p;
            int nB = nA + 1;
            // issue both self rows + both offset pairs up front
            int begA = offs[nA], endA = offs[nA + 1];
            int begB = offs[nB], endB = offs[nB + 1];
            uintx4 vsA = *(const uintx4*)&zin[(size_t)nA * 256 + c0];
            uintx4 vsB = *(const uintx4*)&zin[(size_t)nB * 256 + c0];
            float aA[4], aB[4];
            aA[0] = unpack_pair(vsA[0]);
            aA[1] = unpack_pair(vsA[1]);
            aA[2] = unpack_pair(vsA[2]);
            aA[3] = unpack_pair(vsA[3]);
            BNREL(aA);
            aA[0] *= gs; aA[1] *= gs; aA[2] *= gs; aA[3] *= gs;
            aB[0] = unpack_pair(vsB[0]);
            aB[1] = unpack_pair(vsB[1]);
            aB[2] = unpack_pair(vsB[2]);
            aB[3] = unpack_pair(vsB[3]);
            BNREL(aB);
            aB[0] *= gs; aB[1] *= gs; aB[2] *= gs; aB[3] *= gs;

            int baseA = begA, baseB = begB;
            while (baseA < endA || baseB < endB) {
                bool actA = baseA < endA, actB = baseB < endB;
                int iA0 = 0, iA1 = 0, iA2 = 0, iA3 = 0;
                int iB0 = 0, iB1 = 0, iB2 = 0, iB3 = 0;
                // index round: issue A's and B's csr loads back-to-back
                if (actA) {
                    iA0 = csr_src[baseA];
                    iA1 = (baseA + 1 < endA) ? csr_src[baseA + 1] : iA0;
                    iA2 = (baseA + 2 < endA) ? csr_src[baseA + 2] : iA0;
                    iA3 = (baseA + 3 < endA) ? csr_src[baseA + 3] : iA0;
                }
                if (actB) {
                    iB0 = csr_src[baseB];
                    iB1 = (baseB + 1 < endB) ? csr_src[baseB + 1] : iB0;
                    iB2 = (baseB + 2 < endB) ? csr_src[baseB + 2] : iB0;
                    iB3 = (baseB + 3 < endB) ? csr_src[baseB + 3] : iB0;
                }
                // row round: issue all 8 row loads before any processing
                uintx4 rA0, rA1, rA2, rA3, rB0, rB1, rB2, rB3;
                if (actA) {
                    rA0 = *(const uintx4*)&zin[(size_t)iA0 * 256 + c0];
                    rA1 = *(const uintx4*)&zin[(size_t)iA1 * 256 + c0];
                    rA2 = *(const uintx4*)&zin[(size_t)iA2 * 256 + c0];
                    rA3 = *(const uintx4*)&zin[(size_t)iA3 * 256 + c0];
                }
                if (actB) {
                    rB0 = *(const uintx4*)&zin[(size_t)iB0 * 256 + c0];
                    rB1 = *(const uintx4*)&zin[(size_t)iB1 * 256 + c0];
                    rB2 = *(const uintx4*)&zin[(size_t)iB2 * 256 + c0];
                    rB3 = *(const uintx4*)&zin[(size_t)iB3 * 256 + c0];
                }
                if (actA) {
                    PROCR(rA0, aA);
                    if (baseA + 1 < endA) PROCR(rA1, aA);
                    if (baseA + 2 < endA) PROCR(rA2, aA);
                    if (baseA + 3 < endA) PROCR(rA3, aA);
                    baseA += 4;
                }
                if (actB) {
                    PROCR(rB0, aB);
                    if (baseB + 1 < endB) PROCR(rB1, aB);
                    if (baseB + 2 < endB) PROCR(rB2, aB);
                    if (baseB + 3 < endB) PROCR(rB3, aB);
                    baseB += 4;
                }
            }
            // split + swizzled fragment writes (slots 2p and 2p+1)
            ushortx4 hoA, loA, hoB, loB;
#pragma unroll
            for (int q = 0; q < 4; q++) {
                unsigned short hb, lb;
                split_bf16(aA[q], hb, lb);
                hoA[q] = hb;
                loA[q] = lb;
                split_bf16(aB[q], hb, lb);
                hoB[q] = hb;
                loB[q] = lb;
            }
            int sbA = swz(fb0 + (2 * p) * 16);
            int sbB = swz(fb0 + (2 * p + 1) * 16);
            *(ushortx4*)(lds + sbA) = hoA;
            *(ushortx4*)(lds + sbA + 16384) = loA;
            *(ushortx4*)(lds + sbB) = hoB;
            *(ushortx4*)(lds + sbB + 16384) = loB;
        }
#undef BNREL
#undef PROCR
    }
    __syncthreads();

    // ---------------- P1: acc = Z @ W1 (barrier-free) ----------------------
    floatx4 acc[2][4];
#pragma unroll
    for (int i = 0; i < 2; i++)
#pragma unroll
        for (int j = 0; j < 4; j++) acc[i][j] = (floatx4)0.0f;

#pragma unroll
    for (int kk = 0; kk < 8; kk++) {
        short8 bb0[4], bb1[4];
#pragma unroll
        for (int j = 0; j < 4; j++) {
            bb0[j] = W1m[((size_t)(0 * 8 + kk) * 16 + (w * 4 + j)) * 64 + lane];
            bb1[j] = W1m[((size_t)(1 * 8 + kk) * 16 + (w * 4 + j)) * 64 + lane];
        }
        short8 ah[2], al[2];
#pragma unroll
        for (int mt = 0; mt < 2; mt++) {
            int ib = swz(((kk * 2 + mt) * 64 + lane) * 16);
            ah[mt] = *(short8*)(lds + ib);
            al[mt] = *(short8*)(lds + ib + 16384);
        }
        __builtin_amdgcn_s_setprio(1);
#pragma unroll
        for (int i = 0; i < 2; i++)
#pragma unroll
            for (int j = 0; j < 4; j++) {
                acc[i][j] = __builtin_amdgcn_mfma_f32_16x16x32_bf16(
                    ah[i], bb0[j], acc[i][j], 0, 0, 0);
                acc[i][j] = __builtin_amdgcn_mfma_f32_16x16x32_bf16(
                    ah[i], bb1[j], acc[i][j], 0, 0, 0);
                acc[i][j] = __builtin_amdgcn_mfma_f32_16x16x32_bf16(
                    al[i], bb0[j], acc[i][j], 0, 0, 0);
            }
        __builtin_amdgcn_s_setprio(0);
    }
    __syncthreads();  // Zf dead; Hf takes over

    // ---------------- P2: H = relu(acc + b1) -> A-frag split LDS -----------
#pragma unroll
    for (int j = 0; j < 4; j++) {
        int col = w * 64 + j * 16 + col15;
        float bv = b1[col];
        int kt2 = col >> 5;
        int colg = (col & 31) >> 3;
        int e = col & 7;
#pragma unroll
        for (int i = 0; i < 2; i++) {
            int lane_a = rgrp * 4 + colg * 16;
#pragma unroll
            for (int r = 0; r < 4; r++) {
                float v = fmaxf(acc[i][j][r] + bv, 0.0f);
                unsigned short hb, lb;
                split_bf16(v, hb, lb);
                Hf[(((0 * 8 + kt2) * 2 + i) * 64 + lane_a + r) * 8 + e] = hb;
                Hf[(((1 * 8 + kt2) * 2 + i) * 64 + lane_a + r) * 8 + e] = lb;
            }
        }
    }
    __syncthreads();

    // ---------------- P3: acc2 = H @ W2 (barrier-free) ---------------------
    floatx4 acc2[2][4];
#pragma unroll
    for (int i = 0; i < 2; i++)
#pragma unroll
        for (int j = 0; j < 4; j++) acc2[i][j] = (floatx4)0.0f;

#pragma unroll
    for (int kj = 0; kj < 8; kj++) {
        short8 bb2[2][4];
#pragma unroll
        for (int p = 0; p < 2; p++)
#pragma unroll
            for (int j = 0; j < 4; j++)
                bb2[p][j] =
                    W2m[((size_t)(p * 8 + kj) * 16 + (w * 4 + j)) * 64 + lane];
        short8 ah2[2], al2[2];
#pragma unroll
        for (int mt = 0; mt < 2; mt++) {
            ah2[mt] = *(short8*)&Hf[(((0 * 8 + kj) * 2 + mt) * 64 + lane) * 8];
            al2[mt] = *(short8*)&Hf[(((1 * 8 + kj) * 2 + mt) * 64 + lane) * 8];
        }
        __builtin_amdgcn_s_setprio(1);
#pragma unroll
        for (int i = 0; i < 2; i++)
#pragma unroll
            for (int j = 0; j < 4; j++) {
                acc2[i][j] = __builtin_amdgcn_mfma_f32_16x16x32_bf16(
                    ah2[i], bb2[0][j], acc2[i][j], 0, 0, 0);
                acc2[i][j] = __builtin_amdgcn_mfma_f32_16x16x32_bf16(
                    ah2[i], bb2[1][j], acc2[i][j], 0, 0, 0);
                acc2[i][j] = __builtin_amdgcn_mfma_f32_16x16x32_bf16(
                    al2[i], bb2[0][j], acc2[i][j], 0, 0, 0);
            }
        __builtin_amdgcn_s_setprio(0);
    }
    __syncthreads();  // Hf dead; cf takes over

    // ---------------- P4: stats + LDS transpose + interleaved write --------
#pragma unroll
    for (int j = 0; j < 4; j++) {
        int col = w * 64 + j * 16 + col15;
        float bv = b2[col];
        float csum = 0.f, csq = 0.f;
#pragma unroll
        for (int i = 0; i < 2; i++) {
            int rowb = i * 16 + rgrp * 4;
#pragma unroll
            for (int r = 0; r < 4; r++) {
                float v = acc2[i][j][r] + bv;
                cf[(rowb + r) * 256 + col] = v;
                if (m0 + rowb + r < M) {
                    csum += v;
                    csq += v * v;
                }
            }
        }
        csum += __shfl_xor(csum, 16);
        csum += __shfl_xor(csum, 32);
        csq += __shfl_xor(csq, 16);
        csq += __shfl_xor(csq, 32);
        if (rgrp == 0) {
            atomicAdd(&sums[col], csum);
            atomicAdd(&sumsq[col], csq);
        }
    }
    __syncthreads();
#pragma unroll
    for (int k = 0; k < 8; k++) {
        int fi = (k * 256 + t) * 4;  // flat float idx in 32x256 tile
        int row = fi >> 8, colc = fi & 255;
        int m = m0 + row;
        if (m >= M) continue;
        float4 v4 = *(float4*)&cf[fi];
        uintx4 o;
        o[0] = pack_pair(v4.x);
        o[1] = pack_pair(v4.y);
        o[2] = pack_pair(v4.z);
        o[3] = pack_pair(v4.w);
        *(uintx4*)&C[(size_t)m * 256 + colc] = o;
    }
}

// ---------------- pooling (batch sorted), fused final BN+relu ----------------
__global__ __launch_bounds__(256) void bounds_kernel(const int* __restrict__ batch,
                                                     int* __restrict__ start) {
    int g = blockIdx.x * 256 + threadIdx.x;
    if (g > N_GRAPHS) return;
    int lo = 0, hi = N_NODES;
    while (lo < hi) {
        int mid = (lo + hi) >> 1;
        if (batch[mid] < g) lo = mid + 1;
        else hi = mid;
    }
    start[g] = lo;
}

// Round 9: vectorized segpool — uintx4 (16 B/lane) reads, 4 nodes in flight
// across the 4 waves, LDS cross-wave reduce. 4x fewer load instructions and
// a 4x shorter per-block latency chain than the scalar per-channel loop.
__global__ __launch_bounds__(256) void segpool_kernel(
    const u32* __restrict__ z, const int* __restrict__ start,
    const float* __restrict__ sums, const float* __restrict__ sumsq,
    const float* __restrict__ gammas, const float* __restrict__ betas,
    float* __restrict__ pooled) {
    __shared__ float psum[4][HID];
    int g = blockIdx.x;
    int t = threadIdx.x;
    int lane = t & 63;
    int wv = t >> 6;
    int c0 = lane * 4;
    float sc[4], sh[4];
#pragma unroll
    for (int q = 0; q < 4; q++)
        bn_params(sums, sumsq, gammas, betas, c0 + q, sc[q], sh[q]);
    int beg = start[g], end = start[g + 1];
    float s[4] = {0.f, 0.f, 0.f, 0.f};
    for (int n = beg + wv; n < end; n += 4) {
        uintx4 v4 = *(const uintx4*)&z[(size_t)n * 256 + c0];
#pragma unroll
        for (int q = 0; q < 4; q++) {
            float v = unpack_pair(v4[q]);
            s[q] += fmaxf(v * sc[q] + sh[q], 0.f);
        }
    }
#pragma unroll
    for (int q = 0; q < 4; q++) psum[wv][c0 + q] = s[q];
    __syncthreads();
    // t indexes channel 0..255
    float tot = psum[0][t] + psum[1][t] + psum[2][t] + psum[3][t];
    float inv = 1.0f / fmaxf((float)(end - beg), 1.0f);
    pooled[(size_t)g * HID + t] = tot * inv;
}

// ---------------- readout: 8 graphs per block (Wr1 read 256x fewer times) ----
#define RGK 8
__global__ __launch_bounds__(256) void readout_kernel(
    const float* __restrict__ pooled, const float* __restrict__ Wr1,
    const float* __restrict__ br1, const float* __restrict__ Wr2,
    const float* __restrict__ br2, float* __restrict__ out) {
    __shared__ float p[RGK][HID];
    __shared__ float red[RGK][4];
    int g0 = blockIdx.x * RGK;
    int t = threadIdx.x;
#pragma unroll
    for (int q = 0; q < RGK; q++) p[q][t] = pooled[(size_t)(g0 + q) * HID + t];
    __syncthreads();
    int c = t;
    float acc[RGK];
#pragma unroll
    for (int q = 0; q < RGK; q++) acc[q] = br1[c];
    for (int k = 0; k < HID; k++) {
        float wv = Wr1[k * HID + c];
#pragma unroll
        for (int q = 0; q < RGK; q++) acc[q] = fmaf(p[q][k], wv, acc[q]);
    }
    float w2 = Wr2[c];
#pragma unroll
    for (int q = 0; q < RGK; q++) {
        float v = fmaxf(acc[q], 0.f) * w2;
#pragma unroll
        for (int off = 32; off > 0; off >>= 1) v += __shfl_down(v, off, 64);
        if ((c & 63) == 0) red[q][c >> 6] = v;
    }
    __syncthreads();
    if (t < RGK)
        out[g0 + t] = red[t][0] + red[t][1] + red[t][2] + red[t][3] + br2[0];
}

extern "C" void kernel_launch(void* const* d_in, const int* in_sizes, int n_in,
                              void* d_out, int out_size, void* d_ws, size_t ws_size,
                              hipStream_t stream) {
    const float* x      = (const float*)d_in[0];
    const int*   ei     = (const int*)d_in[1];
    const int*   batch  = (const int*)d_in[2];
    const float* Wp     = (const float*)d_in[3];
    const float* bp     = (const float*)d_in[4];
    const float* eps    = (const float*)d_in[5];
    const float* W1s    = (const float*)d_in[6];
    const float* b1s    = (const float*)d_in[7];
    const float* W2s    = (const float*)d_in[8];
    const float* b2s    = (const float*)d_in[9];
    const float* gammas = (const float*)d_in[10];
    const float* betas  = (const float*)d_in[11];
    const float* Wr1    = (const float*)d_in[12];
    const float* br1    = (const float*)d_in[13];
    const float* Wr2    = (const float*)d_in[14];
    const float* br2    = (const float*)d_in[15];
    float* out = (float*)d_out;

    const size_t ROWS = (size_t)N_NODES + ROW_PAD;
    u32* bufA     = (u32*)d_ws;                    // z ping buffer, interleaved
    u32* bufC     = bufA + ROWS * 256;             // z pong buffer, interleaved
    short8* Wpk8  = (short8*)(bufC + ROWS * 256);  // 10*16384 short8 = 2.62 MB
    float* sums   = (float*)(Wpk8 + 10 * 16384);   // LAYERS*512 (sum|sumsq)
    float* pooled = sums + LAYERS * 512;
    int* start     = (int*)(pooled + (size_t)N_GRAPHS * HID);  // N_GRAPHS+1
    int* deg       = start + N_GRAPHS + 1;
    int* offs      = deg + N_NODES;        // N_NODES+1
    int* cursor    = offs + N_NODES + 1;
    int* csr_src   = cursor + N_NODES;
    int* blocksums = csr_src + N_EDGES;    // N_CHUNKS

    // ---- CSR build + weight packing + zeroing (once per launch) ----
    hipMemsetAsync(deg, 0, N_NODES * sizeof(int), stream);
    hipMemsetAsync(sums, 0, LAYERS * 512 * sizeof(float), stream);
    hist_kernel<<<(N_EDGES + 255) / 256, 256, 0, stream>>>(ei, deg);
    scan1_kernel<<<N_CHUNKS, 256, 0, stream>>>(deg, offs, blocksums);
    scan2_kernel<<<1, 256, 0, stream>>>(blocksums);
    scan3_kernel<<<(N_NODES + 255) / 256, 256, 0, stream>>>(offs, blocksums,
                                                            cursor);
    fill_kernel<<<(N_EDGES + 255) / 256, 256, 0, stream>>>(ei, cursor, csr_src);
    packW_kernel<<<320, 256, 0, stream>>>(W1s, W2s, Wpk8);
    bounds_kernel<<<(N_GRAPHS + 1 + 255) / 256, 256, 0, stream>>>(batch, start);

    // h0 = x @ Wp + bp  -> bufA (interleaved)
    proj_kernel<<<(N_NODES + PROJ_CH - 1) / PROJ_CH, 256, 0, stream>>>(x, Wp, bp,
                                                                       bufA);

    const int MLP_BLOCKS = (N_NODES + 31) / 32;  // 3125, exact (no tail)
    u32* zin = bufA;
    u32* zout = bufC;
    for (int l = 0; l < LAYERS; l++) {
        float* lsums = sums + l * 512;
        float* lsumsq = lsums + 256;
        const float* psums = sums + (l - 1) * 512;  // valid only for l>0
        fused_mlp_kernel<<<MLP_BLOCKS, 256, 0, stream>>>(
            zin, offs, csr_src, eps, l,
            l > 0 ? psums : sums, l > 0 ? psums + 256 : sums,
            gammas + (l > 0 ? (l - 1) : 0) * HID,
            betas + (l > 0 ? (l - 1) : 0) * HID, l > 0 ? 1 : 0,
            Wpk8 + (size_t)l * 16384, b1s + l * HID,
            Wpk8 + (size_t)(5 + l) * 16384, b2s + l * HID, zout, N_NODES,
            lsums, lsumsq);
        u32* tmp = zin; zin = zout; zout = tmp;
    }
    // after 5 swaps, zin holds the final layer output

    segpool_kernel<<<N_GRAPHS, 256, 0, stream>>>(
        zin, start, sums + 4 * 512, sums + 4 * 512 + 256, gammas + 4 * HID,
        betas + 4 * HID, pooled);
    readout_kernel<<<N_GRAPHS / RGK, 256, 0, stream>>>(pooled, Wr1, br1, Wr2, br2,
                                                       out);
}